// Round 20
// baseline (4950.007 us; speedup 1.0000x reference)
//
#include <hip/hip_runtime.h>
#include <hip/hip_bf16.h>

typedef __bf16 bf16;
typedef __bf16 bf16x8 __attribute__((ext_vector_type(8)));
typedef float  f32x4  __attribute__((ext_vector_type(4)));
typedef unsigned long long u64;
typedef unsigned short u16;

// ---------------------------------------------------------------------------
__global__ __launch_bounds__(256) void cast_f32_bf16(const float* __restrict__ in,
                                                     bf16* __restrict__ out) {
    size_t i = ((size_t)blockIdx.x * blockDim.x + threadIdx.x) * 8;
    float4 a = *(const float4*)(in + i);
    float4 b = *(const float4*)(in + i + 4);
    bf16x8 o;
    o[0] = (bf16)a.x; o[1] = (bf16)a.y; o[2] = (bf16)a.z; o[3] = (bf16)a.w;
    o[4] = (bf16)b.x; o[5] = (bf16)b.y; o[6] = (bf16)b.z; o[7] = (bf16)b.w;
    *(bf16x8*)(out + i) = o;
}

// ---------------------------------------------------------------------------
__global__ __launch_bounds__(256) void transpose_cast(const float* __restrict__ in,
                                                      bf16* __restrict__ out,
                                                      int R, int C) {
    __shared__ float tile[32][33];
    int c0 = blockIdx.x * 32, r0 = blockIdx.y * 32;
    int tx = threadIdx.x & 31, ty = threadIdx.x >> 5;
    #pragma unroll
    for (int i = 0; i < 32; i += 8)
        tile[ty + i][tx] = in[(size_t)(r0 + ty + i) * C + c0 + tx];
    __syncthreads();
    #pragma unroll
    for (int i = 0; i < 32; i += 8)
        out[(size_t)(c0 + ty + i) * R + r0 + tx] = (bf16)tile[tx][ty + i];
}

// ---------------------------------------------------------------------------
template<bool BF16_OUT, bool HAS_BIAS>
__global__ __launch_bounds__(256) void gemm128(const bf16* __restrict__ A,
                                               const bf16* __restrict__ Bt,
                                               const float* __restrict__ bias,
                                               void* __restrict__ Cout,
                                               int M, int N, int K) {
    __shared__ bf16 sA[128][72];
    __shared__ bf16 sB[128][72];
    const int tid = threadIdx.x, lane = tid & 63, w = tid >> 6;
    const int wr = w >> 1, wc = w & 1;
    const int m0 = blockIdx.y * 128, n0 = blockIdx.x * 128;
    const int ml = lane & 15, kb = (lane >> 4) * 8;

    f32x4 acc[4][4] = {};
    const bf16* Ab = A  + (size_t)m0 * K;
    const bf16* Bb = Bt + (size_t)n0 * K;

    for (int kc = 0; kc < K; kc += 64) {
        #pragma unroll
        for (int i = 0; i < 4; ++i) {
            int c = tid + 256 * i;
            int row = c >> 3, col = (c & 7) * 8;
            *(uint4*)&sA[row][col] = *(const uint4*)(Ab + (size_t)row * K + kc + col);
            *(uint4*)&sB[row][col] = *(const uint4*)(Bb + (size_t)row * K + kc + col);
        }
        __syncthreads();
        #pragma unroll
        for (int ks = 0; ks < 2; ++ks) {
            bf16x8 af[4], bfr[4];
            #pragma unroll
            for (int i = 0; i < 4; ++i)
                af[i] = *(const bf16x8*)&sA[wr * 64 + i * 16 + ml][ks * 32 + kb];
            #pragma unroll
            for (int i = 0; i < 4; ++i)
                bfr[i] = *(const bf16x8*)&sB[wc * 64 + i * 16 + ml][ks * 32 + kb];
            #pragma unroll
            for (int mi = 0; mi < 4; ++mi)
                #pragma unroll
                for (int ni = 0; ni < 4; ++ni)
                    acc[mi][ni] = __builtin_amdgcn_mfma_f32_16x16x32_bf16(
                        af[mi], bfr[ni], acc[mi][ni], 0, 0, 0);
        }
        __syncthreads();
    }
    const int rbase = (lane >> 4) * 4;
    #pragma unroll
    for (int mi = 0; mi < 4; ++mi) {
        #pragma unroll
        for (int ni = 0; ni < 4; ++ni) {
            int col = n0 + wc * 64 + ni * 16 + ml;
            float bv = HAS_BIAS ? bias[col] : 0.f;
            #pragma unroll
            for (int r = 0; r < 4; ++r) {
                int row = m0 + wr * 64 + mi * 16 + rbase + r;
                float v = acc[mi][ni][r] + bv;
                if constexpr (BF16_OUT)
                    ((bf16*)Cout)[(size_t)row * N + col] = (bf16)v;
                else
                    ((float*)Cout)[(size_t)row * N + col] = v;
            }
        }
    }
}

// ---------------------------------------------------------------------------
// FRAGMENT-MAJOR h layout (per 128KB slot):
//   byte(b, j) = (b>>4)*32768 + (j>>5)*1024 + ((j>>3)&3)*256 + (b&15)*16 + (j&7)*2
// Consumer wave's per-ks load instruction covers a CONTIGUOUS 1 KB.

// Full-K pass (roles 0/2): 48-row LDS slice (2048B rows), 32 quads.
__device__ __forceinline__ void mm_step(const char* sW, const char* hslot,
                                        int wv, int lane, int kb, int ml,
                                        f32x4 acc[3]) {
    const char* rowp = hslot + wv * 32768 + (lane >> 4) * 256 + ml * 16;
    uint4 hq[32];
    #pragma unroll
    for (int ks = 0; ks < 32; ++ks)
        asm volatile("global_load_dwordx4 %0, %1, off"
                     : "=v"(hq[ks]) : "v"(rowp + ks * 1024) : "memory");
    asm volatile("s_waitcnt vmcnt(16)" ::: "memory");
    __builtin_amdgcn_sched_barrier(0);
    #pragma unroll
    for (int ks = 0; ks < 16; ++ks) {
        bf16x8 af = __builtin_bit_cast(bf16x8, hq[ks]);
        #pragma unroll
        for (int g = 0; g < 3; ++g) {
            int brow = g * 16 + ml;
            int addr = brow * 2048 + (ks * 32 + kb) * 2;
            addr ^= (brow & 7) << 4;
            bf16x8 bw = *(const bf16x8*)(sW + addr);
            acc[g] = __builtin_amdgcn_mfma_f32_16x16x32_bf16(af, bw, acc[g], 0, 0, 0);
        }
    }
    asm volatile("s_waitcnt vmcnt(0)" ::: "memory");
    __builtin_amdgcn_sched_barrier(0);
    #pragma unroll
    for (int ks = 16; ks < 32; ++ks) {
        bf16x8 af = __builtin_bit_cast(bf16x8, hq[ks]);
        #pragma unroll
        for (int g = 0; g < 3; ++g) {
            int brow = g * 16 + ml;
            int addr = brow * 2048 + (ks * 32 + kb) * 2;
            addr ^= (brow & 7) << 4;
            bf16x8 bw = *(const bf16x8*)(sW + addr);
            acc[g] = __builtin_amdgcn_mfma_f32_16x16x32_bf16(af, bw, acc[g], 0, 0, 0);
        }
    }
}

// K-half pass (role 1): 96-row LDS slice (1024B rows, 32 cols x 3 gates),
// 16 quads, K range [kh*512, kh*512+512).
__device__ __forceinline__ void mm_step16(const char* sW, const char* hslot,
                                          int kh, int wv, int lane, int kb, int ml,
                                          f32x4 acc[3][2]) {
    const char* rowp = hslot + wv * 32768 + (lane >> 4) * 256 + ml * 16 + kh * 16384;
    uint4 hq[16];
    #pragma unroll
    for (int ks = 0; ks < 16; ++ks)
        asm volatile("global_load_dwordx4 %0, %1, off"
                     : "=v"(hq[ks]) : "v"(rowp + ks * 1024) : "memory");
    asm volatile("s_waitcnt vmcnt(8)" ::: "memory");
    __builtin_amdgcn_sched_barrier(0);
    #pragma unroll
    for (int ks = 0; ks < 8; ++ks) {
        bf16x8 af = __builtin_bit_cast(bf16x8, hq[ks]);
        #pragma unroll
        for (int g = 0; g < 3; ++g)
            #pragma unroll
            for (int ct = 0; ct < 2; ++ct) {
                int brow = g * 32 + ct * 16 + ml;
                int addr = brow * 1024 + (((ks * 32 + kb) * 2) ^ ((brow & 7) << 4));
                bf16x8 bw = *(const bf16x8*)(sW + addr);
                acc[g][ct] = __builtin_amdgcn_mfma_f32_16x16x32_bf16(af, bw, acc[g][ct], 0, 0, 0);
            }
    }
    asm volatile("s_waitcnt vmcnt(0)" ::: "memory");
    __builtin_amdgcn_sched_barrier(0);
    #pragma unroll
    for (int ks = 8; ks < 16; ++ks) {
        bf16x8 af = __builtin_bit_cast(bf16x8, hq[ks]);
        #pragma unroll
        for (int g = 0; g < 3; ++g)
            #pragma unroll
            for (int ct = 0; ct < 2; ++ct) {
                int brow = g * 32 + ct * 16 + ml;
                int addr = brow * 1024 + (((ks * 32 + kb) * 2) ^ ((brow & 7) << 4));
                bf16x8 bw = *(const bf16x8*)(sW + addr);
                acc[g][ct] = __builtin_amdgcn_mfma_f32_16x16x32_bf16(af, bw, acc[g][ct], 0, 0, 0);
            }
    }
}

// packed col-pair store into the FRAGMENT layout (j even; pair shares a unit)
__device__ __forceinline__ void store_pair_frag(char* slot, int b, int j,
                                                unsigned short v, int ml) {
    unsigned nb = (unsigned)__shfl_xor((int)(unsigned)v, 1, 64);
    if ((ml & 1) == 0) {
        unsigned pk = (unsigned)v | (nb << 16);
        size_t off = (size_t)((b >> 4) * 32768 + (j >> 5) * 1024 +
                              ((j >> 3) & 3) * 256 + (b & 15) * 16 + (j & 7) * 2);
        __hip_atomic_store((unsigned*)(slot + off), pk,
                           __ATOMIC_RELAXED, __HIP_MEMORY_SCOPE_AGENT);
    }
}

// coalesced 64-lane poll of one u16 flag group (2 cache lines, 0.21us grain)
__device__ __forceinline__ void poll1(const u16* a, unsigned ta, int lane) {
    while (true) {
        unsigned fa = (unsigned)__hip_atomic_load(a + lane, __ATOMIC_RELAXED,
                                                  __HIP_MEMORY_SCOPE_AGENT);
        if (__all((int)(fa >= ta))) break;
        __builtin_amdgcn_s_sleep(8);
    }
    asm volatile("" ::: "memory");
}

__device__ __forceinline__ void publish1(u16* s1, unsigned val, int lane) {
    asm volatile("s_waitcnt vmcnt(0)" ::: "memory");
    if (lane == 0)
        __hip_atomic_store(s1, (u16)val, __ATOMIC_RELAXED, __HIP_MEMORY_SCOPE_AGENT);
}
__device__ __forceinline__ void publish2(u16* s1, u16* s2, unsigned val, int lane) {
    asm volatile("s_waitcnt vmcnt(0)" ::: "memory");
    if (lane == 0) {
        __hip_atomic_store(s1, (u16)val, __ATOMIC_RELAXED, __HIP_MEMORY_SCOPE_AGENT);
        __hip_atomic_store(s2, (u16)val, __ATOMIC_RELAXED, __HIP_MEMORY_SCOPE_AGENT);
    }
}

// ---------------------------------------------------------------------------
// Fused 2-layer GRU pipeline (r19 + K-split role1), 192 blocks x 256 thr:
//  role 0 (blk 0..63):   layer-1 scan -> h1f[t] (fragment, 512 slots)
//  role 1 (blk 64..127): 32 col-groups x 2 K-halves; partial gx2 halves ->
//                        16-slot ring (bf16, both halves); role2 sums them.
//                        Each block reads only HALF of h1 (64 KB vs 128 KB).
//  role 2 (blk 128..191):layer-2 scan -> hs2f ring (fragment) + hs2row
__global__ __launch_bounds__(256, 1) void gru_fused(
    const bf16* __restrict__ WH1T, const bf16* __restrict__ W2fT,
    const bf16* __restrict__ WH2T, const bf16* __restrict__ gx1,
    const float* __restrict__ pad, const float* __restrict__ b2,
    char* __restrict__ h1f,      // 512 x 131072 B (fragment)
    bf16* __restrict__ gx2ring,  // 16 x 2 x [3][1024][64]  (transposed halves)
    char* __restrict__ hs2f,     // 16 x 131072 B (fragment ring)
    bf16* __restrict__ hs2row,   // [512*64][1024] row-major
    u16* __restrict__ f1s, u16* __restrict__ f1c,
    u16* __restrict__ f2,
    u16* __restrict__ f3s, u16* __restrict__ f3c) {
    extern __shared__ __align__(16) char sW[];   // 96 KB, layout per role

    const int tid = threadIdx.x, lane = tid & 63, wv = tid >> 6;
    const int role = blockIdx.x >> 6, jg = blockIdx.x & 63;
    const int j0 = jg * 16;
    const int ml = lane & 15, kb = (lane >> 4) * 8;
    const int rbase = (lane >> 4) * 4;
    const int bbase = wv * 16 + rbase;
    const int jml = j0 + ml;

    // ---- stage this role's weight slice into LDS
    if (role == 1) {
        // 96 rows x 1024B: rows = gate*32 + cx (cx 0..31), K range kh*512..+512
        const int cgrp = jg >> 1, kh = jg & 1;
        #pragma unroll 1
        for (int i = 0; i < 24; ++i) {
            int c = tid + 256 * i;            // 6144 chunks of 16B
            int row = c >> 6;                 // 0..95
            int off = (c & 63) * 16;
            int gate = row >> 5, cx = row & 31;
            const bf16* src = W2fT + (size_t)(gate * 1024 + cgrp * 32 + cx) * 1024
                              + kh * 512 + off / 2;
            *(uint4*)(sW + row * 1024 + (off ^ ((row & 7) << 4))) = *(const uint4*)src;
        }
    } else {
        // 48 rows x 2048B: rows = gate*16 + j (j 0..15), full K
        const bf16* Wsrc = (role == 0) ? WH1T : WH2T;
        #pragma unroll 1
        for (int i = 0; i < 24; ++i) {
            int c = tid + 256 * i;
            int rr = c >> 7;
            int off = (c & 127) * 16;
            int gate = rr >> 4, j = rr & 15;
            const bf16* src = Wsrc + (size_t)(gate * 1024 + j0 + j) * 1024 + off / 2;
            *(uint4*)(sW + rr * 2048 + (off ^ ((rr & 7) << 4))) = *(const uint4*)src;
        }
    }
    __syncthreads();   // sW read-only afterwards; waves free-run

    if (role == 0) {
        // ================= layer-1 scan =================
        u16* fown = f1s + wv * 64;
        float hreg[4] = {0.f, 0.f, 0.f, 0.f};
        float gxv[12]; float4 pv;
        #pragma unroll
        for (int r = 0; r < 4; ++r) {
            size_t b = (size_t)(bbase + r);
            gxv[r * 3 + 0] = (float)gx1[b * 3072 + jml];
            gxv[r * 3 + 1] = (float)gx1[b * 3072 + 1024 + jml];
            gxv[r * 3 + 2] = (float)gx1[b * 3072 + 2048 + jml];
        }
        pv = *(const float4*)(pad + bbase);

        for (int t = 0; t < 512; ++t) {
            f32x4 acc[3] = {};
            if (t > 0) {
                poll1(fown, (unsigned)t, lane);
                mm_step(sW, h1f + (size_t)(t - 1) * 131072, wv, lane, kb, ml, acc);
            }
            unsigned short hpk[4];
            #pragma unroll
            for (int r = 0; r < 4; ++r) {
                float rr = 1.f / (1.f + __expf(-(gxv[r * 3 + 0] + acc[0][r])));
                float zz = 1.f / (1.f + __expf(-(gxv[r * 3 + 1] + acc[1][r])));
                float nn = tanhf(gxv[r * 3 + 2] + rr * acc[2][r]);
                float hold = hreg[r];
                float hn = (1.f - zz) * nn + zz * hold;
                float p = (r == 0) ? pv.x : (r == 1) ? pv.y : (r == 2) ? pv.z : pv.w;
                hn = p * hold + (1.f - p) * hn;
                hreg[r] = hn;
                hpk[r] = __builtin_bit_cast(unsigned short, (bf16)hn);
            }
            char* hst = h1f + (size_t)t * 131072;
            #pragma unroll
            for (int r = 0; r < 4; ++r)
                store_pair_frag(hst, bbase + r, jml, hpk[r], ml);
            publish2(fown + jg, f1c + wv * 64 + jg, (unsigned)(t + 1), lane);
            {   // prefetch gx1 + pad for t+1 (cached; drains during next poll)
                int tn = (t < 511) ? t + 1 : 511;
                const bf16* gxt = gx1 + (size_t)tn * 64 * 3072;
                #pragma unroll
                for (int r = 0; r < 4; ++r) {
                    size_t b = (size_t)(bbase + r);
                    gxv[r * 3 + 0] = (float)gxt[b * 3072 + jml];
                    gxv[r * 3 + 1] = (float)gxt[b * 3072 + 1024 + jml];
                    gxv[r * 3 + 2] = (float)gxt[b * 3072 + 2048 + jml];
                }
                pv = *(const float4*)(pad + tn * 64 + bbase);
            }
        }
    } else if (role == 1) {
        // ================= gx2 partial producer (K-half) =================
        const int cgrp = jg >> 1, kh = jg & 1;
        u16* fsrc = f1c + wv * 64;
        u16* fbp  = f3c + wv * 64;
        for (int t = 0; t < 512; ++t) {
            poll1(fsrc, (unsigned)(t + 1), lane);     // h1[t] ready
            f32x4 acc2[3][2] = {};
            mm_step16(sW, h1f + (size_t)t * 131072, kh, wv, lane, kb, ml, acc2);
            if (t >= 16)                              // back-pressure gates STORES
                poll1(fbp, (unsigned)(t - 15), lane);
            // store bf16 partials: [kh][g][col][64 rows], one 8B store per (g,ct)
            bf16* dst = gx2ring + (size_t)(t & 15) * 393216 + (size_t)kh * 196608;
            #pragma unroll
            for (int g = 0; g < 3; ++g)
                #pragma unroll
                for (int ct = 0; ct < 2; ++ct) {
                    int col = cgrp * 32 + ct * 16 + ml;
                    unsigned short w0 = __builtin_bit_cast(unsigned short, (bf16)acc2[g][ct][0]);
                    unsigned short w1 = __builtin_bit_cast(unsigned short, (bf16)acc2[g][ct][1]);
                    unsigned short w2 = __builtin_bit_cast(unsigned short, (bf16)acc2[g][ct][2]);
                    unsigned short w3 = __builtin_bit_cast(unsigned short, (bf16)acc2[g][ct][3]);
                    u64 pk = (u64)w0 | ((u64)w1 << 16) | ((u64)w2 << 32) | ((u64)w3 << 48);
                    __hip_atomic_store((u64*)(dst + ((size_t)(g * 1024 + col)) * 64 + bbase),
                                       pk, __ATOMIC_RELAXED, __HIP_MEMORY_SCOPE_AGENT);
                }
            publish1(f2 + wv * 64 + jg, (unsigned)(t + 1), lane);
        }
    } else {
        // ================= layer-2 scan =================
        u16* fown = f3s + wv * 64;
        u16* fgx  = f2 + wv * 64;
        float b2v[3] = {b2[jml], b2[1024 + jml], b2[2048 + jml]};
        float hreg[4] = {0.f, 0.f, 0.f, 0.f};
        float4 pv = *(const float4*)(pad + bbase);

        for (int t = 0; t < 512; ++t) {
            poll1(fgx, (unsigned)(t + 1), lane);      // both gx2 halves ready
            // issue gx2 partial loads; they drain during the fown poll below
            const bf16* gsl = gx2ring + (size_t)(t & 15) * 393216;
            u64 gq[2][3];
            #pragma unroll
            for (int h = 0; h < 2; ++h)
                #pragma unroll
                for (int g = 0; g < 3; ++g)
                    gq[h][g] = __hip_atomic_load(
                        (const u64*)(gsl + (size_t)h * 196608 +
                                     ((size_t)(g * 1024 + jml)) * 64 + bbase),
                        __ATOMIC_RELAXED, __HIP_MEMORY_SCOPE_AGENT);
            f32x4 acc[3] = {};
            if (t > 0) {
                poll1(fown, (unsigned)t, lane);       // hs2f[t-1] ready
                mm_step(sW, hs2f + (size_t)((t - 1) & 15) * 131072, wv, lane, kb, ml, acc);
            }
            unsigned short hpk[4];
            #pragma unroll
            for (int r = 0; r < 4; ++r) {
                float gr = (float)__builtin_bit_cast(bf16, (unsigned short)(gq[0][0] >> (r * 16)))
                         + (float)__builtin_bit_cast(bf16, (unsigned short)(gq[1][0] >> (r * 16)))
                         + b2v[0];
                float gz = (float)__builtin_bit_cast(bf16, (unsigned short)(gq[0][1] >> (r * 16)))
                         + (float)__builtin_bit_cast(bf16, (unsigned short)(gq[1][1] >> (r * 16)))
                         + b2v[1];
                float gn = (float)__builtin_bit_cast(bf16, (unsigned short)(gq[0][2] >> (r * 16)))
                         + (float)__builtin_bit_cast(bf16, (unsigned short)(gq[1][2] >> (r * 16)))
                         + b2v[2];
                float rr = 1.f / (1.f + __expf(-(gr + acc[0][r])));
                float zz = 1.f / (1.f + __expf(-(gz + acc[1][r])));
                float nn = tanhf(gn + rr * acc[2][r]);
                float hold = hreg[r];
                float hn = (1.f - zz) * nn + zz * hold;
                float p = (r == 0) ? pv.x : (r == 1) ? pv.y : (r == 2) ? pv.z : pv.w;
                hn = p * hold + (1.f - p) * hn;
                hreg[r] = hn;
                hpk[r] = __builtin_bit_cast(unsigned short, (bf16)hn);
            }
            // fragment store for the recurrence ring (sc)
            char* hstf = hs2f + (size_t)(t & 15) * 131072;
            #pragma unroll
            for (int r = 0; r < 4; ++r)
                store_pair_frag(hstf, bbase + r, jml, hpk[r], ml);
            // row-major plain store for the final GEMM
            bf16* hstr = hs2row + (size_t)t * 65536;
            #pragma unroll
            for (int r = 0; r < 4; ++r) {
                unsigned nb = (unsigned)__shfl_xor((int)(unsigned)hpk[r], 1, 64);
                if ((ml & 1) == 0) {
                    unsigned pk = (unsigned)hpk[r] | (nb << 16);
                    *(unsigned*)(hstr + (size_t)(bbase + r) * 1024 + jml) = pk;
                }
            }
            publish2(fown + jg, f3c + wv * 64 + jg, (unsigned)(t + 1), lane);
            int tn = (t < 511) ? t + 1 : 511;
            pv = *(const float4*)(pad + tn * 64 + bbase);
        }
    }
}

// ---------------------------------------------------------------------------
extern "C" void kernel_launch(void* const* d_in, const int* in_sizes, int n_in,
                              void* d_out, int out_size, void* d_ws, size_t ws_size,
                              hipStream_t stream) {
    const float* x    = (const float*)d_in[0];
    const float* pad  = (const float*)d_in[1];
    const float* Wih1 = (const float*)d_in[2];
    const float* Whh1 = (const float*)d_in[3];
    const float* b1   = (const float*)d_in[4];
    const float* Who1 = (const float*)d_in[5];
    const float* Wih2 = (const float*)d_in[6];
    const float* Whh2 = (const float*)d_in[7];
    const float* b2   = (const float*)d_in[8];
    const float* Who2 = (const float*)d_in[9];
    float* out_f = (float*)d_out;

    char* p = (char*)d_ws;
    bf16* xb      = (bf16*)p; p += (size_t)32768 * 1024 * 2;  //  64MB
    bf16* gxb     = (bf16*)p; p += (size_t)32768 * 3072 * 2;  // 192MB (gx1)
    char* h1f     = p;        p += (size_t)512 * 131072;      //  64MB (fragment)
    bf16* hs2row  = (bf16*)p; p += (size_t)32768 * 1024 * 2;  //  64MB (row-major)
    char* hs2f    = p;        p += (size_t)16 * 131072;       //   2MB (fragment ring)
    bf16* gx2ring = (bf16*)p; p += (size_t)16 * 393216 * 2;   //  12MB (2 halves)
    bf16* WT1     = (bf16*)p; p += (size_t)3072 * 1024 * 2;   //   6MB
    bf16* who1b   = (bf16*)p; p += (size_t)1024 * 1024 * 2;   //   2MB
    bf16* W2fT    = (bf16*)p; p += (size_t)3072 * 1024 * 2;   //   6MB
    bf16* WH1     = (bf16*)p; p += (size_t)3072 * 1024 * 2;   //   6MB
    bf16* WH2     = (bf16*)p; p += (size_t)3072 * 1024 * 2;   //   6MB
    u16* flags = (u16*)p; p += 8192;
    u16* f1s = flags,        * f1c = flags + 256;
    u16* f2  = flags + 512;
    u16* f3s = flags + 768,  * f3c = flags + 1024;

    hipFuncSetAttribute((const void*)gru_fused,
                        hipFuncAttributeMaxDynamicSharedMemorySize, 131072);

    // 1. x -> bf16
    cast_f32_bf16<<<16384, 256, 0, stream>>>(x, xb);
    // 2. gx1 = x @ Wih1 + b1
    transpose_cast<<<dim3(96, 32), 256, 0, stream>>>(Wih1, WT1, 1024, 3072);
    gemm128<true, true><<<dim3(24, 256), 256, 0, stream>>>(
        xb, WT1, b1, gxb, 32768, 3072, 1024);
    // 3. W2fT = (Who1 @ Wih2)^T  (verified recipe)
    transpose_cast<<<dim3(96, 32), 256, 0, stream>>>(Wih2, WT1, 1024, 3072);
    cast_f32_bf16<<<512, 256, 0, stream>>>(Who1, who1b);
    gemm128<true, false><<<dim3(8, 24), 256, 0, stream>>>(
        WT1, who1b, nullptr, W2fT, 3072, 1024, 1024);
    // 4. recurrent weights; Who2T into WT1 (stream-ordered reuse)
    transpose_cast<<<dim3(96, 32), 256, 0, stream>>>(Whh1, WH1, 1024, 3072);
    transpose_cast<<<dim3(96, 32), 256, 0, stream>>>(Whh2, WH2, 1024, 3072);
    transpose_cast<<<dim3(32, 32), 256, 0, stream>>>(Who2, WT1, 1024, 1024);
    hipMemsetAsync(flags, 0, 8192, stream);
    // 5. fused pipelined 2-layer scan (fragment-major h, K-split gx2)
    gru_fused<<<192, 256, 98304, stream>>>(WH1, W2fT, WH2, gxb, pad, b2,
                                           h1f, gx2ring, hs2f, hs2row,
                                           f1s, f1c, f2, f3s, f3c);
    // 6. out = hs2 @ Who2 (f32)
    gemm128<false, false><<<dim3(8, 256), 256, 0, stream>>>(
        hs2row, WT1, nullptr, out_f, 32768, 1024, 1024);
}

// Round 21
// 4755.314 us; speedup vs baseline: 1.0409x; 1.0409x over previous
//
#include <hip/hip_runtime.h>
#include <hip/hip_bf16.h>

typedef __bf16 bf16;
typedef __bf16 bf16x8 __attribute__((ext_vector_type(8)));
typedef float  f32x4  __attribute__((ext_vector_type(4)));
typedef unsigned long long u64;
typedef unsigned short u16;

// ---------------------------------------------------------------------------
__global__ __launch_bounds__(256) void cast_f32_bf16(const float* __restrict__ in,
                                                     bf16* __restrict__ out) {
    size_t i = ((size_t)blockIdx.x * blockDim.x + threadIdx.x) * 8;
    float4 a = *(const float4*)(in + i);
    float4 b = *(const float4*)(in + i + 4);
    bf16x8 o;
    o[0] = (bf16)a.x; o[1] = (bf16)a.y; o[2] = (bf16)a.z; o[3] = (bf16)a.w;
    o[4] = (bf16)b.x; o[5] = (bf16)b.y; o[6] = (bf16)b.z; o[7] = (bf16)b.w;
    *(bf16x8*)(out + i) = o;
}

// ---------------------------------------------------------------------------
__global__ __launch_bounds__(256) void transpose_cast(const float* __restrict__ in,
                                                      bf16* __restrict__ out,
                                                      int R, int C) {
    __shared__ float tile[32][33];
    int c0 = blockIdx.x * 32, r0 = blockIdx.y * 32;
    int tx = threadIdx.x & 31, ty = threadIdx.x >> 5;
    #pragma unroll
    for (int i = 0; i < 32; i += 8)
        tile[ty + i][tx] = in[(size_t)(r0 + ty + i) * C + c0 + tx];
    __syncthreads();
    #pragma unroll
    for (int i = 0; i < 32; i += 8)
        out[(size_t)(c0 + ty + i) * R + r0 + tx] = (bf16)tile[tx][ty + i];
}

// ---------------------------------------------------------------------------
template<bool BF16_OUT, bool HAS_BIAS>
__global__ __launch_bounds__(256) void gemm128(const bf16* __restrict__ A,
                                               const bf16* __restrict__ Bt,
                                               const float* __restrict__ bias,
                                               void* __restrict__ Cout,
                                               int M, int N, int K) {
    __shared__ bf16 sA[128][72];
    __shared__ bf16 sB[128][72];
    const int tid = threadIdx.x, lane = tid & 63, w = tid >> 6;
    const int wr = w >> 1, wc = w & 1;
    const int m0 = blockIdx.y * 128, n0 = blockIdx.x * 128;
    const int ml = lane & 15, kb = (lane >> 4) * 8;

    f32x4 acc[4][4] = {};
    const bf16* Ab = A  + (size_t)m0 * K;
    const bf16* Bb = Bt + (size_t)n0 * K;

    for (int kc = 0; kc < K; kc += 64) {
        #pragma unroll
        for (int i = 0; i < 4; ++i) {
            int c = tid + 256 * i;
            int row = c >> 3, col = (c & 7) * 8;
            *(uint4*)&sA[row][col] = *(const uint4*)(Ab + (size_t)row * K + kc + col);
            *(uint4*)&sB[row][col] = *(const uint4*)(Bb + (size_t)row * K + kc + col);
        }
        __syncthreads();
        #pragma unroll
        for (int ks = 0; ks < 2; ++ks) {
            bf16x8 af[4], bfr[4];
            #pragma unroll
            for (int i = 0; i < 4; ++i)
                af[i] = *(const bf16x8*)&sA[wr * 64 + i * 16 + ml][ks * 32 + kb];
            #pragma unroll
            for (int i = 0; i < 4; ++i)
                bfr[i] = *(const bf16x8*)&sB[wc * 64 + i * 16 + ml][ks * 32 + kb];
            #pragma unroll
            for (int mi = 0; mi < 4; ++mi)
                #pragma unroll
                for (int ni = 0; ni < 4; ++ni)
                    acc[mi][ni] = __builtin_amdgcn_mfma_f32_16x16x32_bf16(
                        af[mi], bfr[ni], acc[mi][ni], 0, 0, 0);
        }
        __syncthreads();
    }
    const int rbase = (lane >> 4) * 4;
    #pragma unroll
    for (int mi = 0; mi < 4; ++mi) {
        #pragma unroll
        for (int ni = 0; ni < 4; ++ni) {
            int col = n0 + wc * 64 + ni * 16 + ml;
            float bv = HAS_BIAS ? bias[col] : 0.f;
            #pragma unroll
            for (int r = 0; r < 4; ++r) {
                int row = m0 + wr * 64 + mi * 16 + rbase + r;
                float v = acc[mi][ni][r] + bv;
                if constexpr (BF16_OUT)
                    ((bf16*)Cout)[(size_t)row * N + col] = (bf16)v;
                else
                    ((float*)Cout)[(size_t)row * N + col] = v;
            }
        }
    }
}

// ---------------------------------------------------------------------------
// FRAGMENT-MAJOR h layout (per 128KB slot):
//   byte(b, j) = (b>>4)*32768 + (j>>5)*1024 + ((j>>3)&3)*256 + (b&15)*16 + (j&7)*2
// -> consumer wave's per-ks load instruction covers a CONTIGUOUS 1 KB
//    (8 full 128B lines) instead of 16 scattered 64B segments.
__device__ __forceinline__ void mm_step(const char* sW, const char* hslot,
                                        int wv, int lane, int kb, int ml,
                                        f32x4 acc[3]) {
    const char* rowp = hslot + wv * 32768 + (lane >> 4) * 256 + ml * 16;
    uint4 hq[32];
    #pragma unroll
    for (int ks = 0; ks < 32; ++ks)
        asm volatile("global_load_dwordx4 %0, %1, off"
                     : "=v"(hq[ks]) : "v"(rowp + ks * 1024) : "memory");
    asm volatile("s_waitcnt vmcnt(16)" ::: "memory");
    __builtin_amdgcn_sched_barrier(0);
    #pragma unroll
    for (int ks = 0; ks < 16; ++ks) {
        bf16x8 af = __builtin_bit_cast(bf16x8, hq[ks]);
        #pragma unroll
        for (int g = 0; g < 3; ++g) {
            int brow = g * 16 + ml;
            int addr = brow * 2048 + (ks * 32 + kb) * 2;
            addr ^= (brow & 7) << 4;
            bf16x8 bw = *(const bf16x8*)(sW + addr);
            acc[g] = __builtin_amdgcn_mfma_f32_16x16x32_bf16(af, bw, acc[g], 0, 0, 0);
        }
    }
    asm volatile("s_waitcnt vmcnt(0)" ::: "memory");
    __builtin_amdgcn_sched_barrier(0);
    #pragma unroll
    for (int ks = 16; ks < 32; ++ks) {
        bf16x8 af = __builtin_bit_cast(bf16x8, hq[ks]);
        #pragma unroll
        for (int g = 0; g < 3; ++g) {
            int brow = g * 16 + ml;
            int addr = brow * 2048 + (ks * 32 + kb) * 2;
            addr ^= (brow & 7) << 4;
            bf16x8 bw = *(const bf16x8*)(sW + addr);
            acc[g] = __builtin_amdgcn_mfma_f32_16x16x32_bf16(af, bw, acc[g], 0, 0, 0);
        }
    }
}

// packed col-pair store into the FRAGMENT layout (j even; pair shares a unit)
__device__ __forceinline__ void store_pair_frag(char* slot, int b, int j,
                                                unsigned short v, int ml) {
    unsigned nb = (unsigned)__shfl_xor((int)(unsigned)v, 1, 64);
    if ((ml & 1) == 0) {
        unsigned pk = (unsigned)v | (nb << 16);
        size_t off = (size_t)((b >> 4) * 32768 + (j >> 5) * 1024 +
                              ((j >> 3) & 3) * 256 + (b & 15) * 16 + (j & 7) * 2);
        __hip_atomic_store((unsigned*)(slot + off), pk,
                           __ATOMIC_RELAXED, __HIP_MEMORY_SCOPE_AGENT);
    }
}

// coalesced 64-lane poll of one u16 flag group (2 cache lines, 0.21us grain)
__device__ __forceinline__ void poll1(const u16* a, unsigned ta, int lane) {
    while (true) {
        unsigned fa = (unsigned)__hip_atomic_load(a + lane, __ATOMIC_RELAXED,
                                                  __HIP_MEMORY_SCOPE_AGENT);
        if (__all((int)(fa >= ta))) break;
        __builtin_amdgcn_s_sleep(8);
    }
    asm volatile("" ::: "memory");
}

__device__ __forceinline__ void publish1(u16* s1, unsigned val, int lane) {
    asm volatile("s_waitcnt vmcnt(0)" ::: "memory");
    if (lane == 0)
        __hip_atomic_store(s1, (u16)val, __ATOMIC_RELAXED, __HIP_MEMORY_SCOPE_AGENT);
}
__device__ __forceinline__ void publish2(u16* s1, u16* s2, unsigned val, int lane) {
    asm volatile("s_waitcnt vmcnt(0)" ::: "memory");
    if (lane == 0) {
        __hip_atomic_store(s1, (u16)val, __ATOMIC_RELAXED, __HIP_MEMORY_SCOPE_AGENT);
        __hip_atomic_store(s2, (u16)val, __ATOMIC_RELAXED, __HIP_MEMORY_SCOPE_AGENT);
    }
}

// ---------------------------------------------------------------------------
// Fused 2-layer GRU pipeline (r16 protocol + fragment-major h), 192 blocks:
//  role 0 (blk 0..63):   layer-1 scan -> h1f[t] (fragment, 512 slots)
//  role 1 (blk 64..127): gx2[t] = h1[t] @ W2f -> 16-slot transposed ring
//  role 2 (blk 128..191):layer-2 scan -> hs2f ring (fragment, recurrence)
//                        + hs2row (row-major, plain stores, final GEMM input)
__global__ __launch_bounds__(256, 1) void gru_fused(
    const bf16* __restrict__ WH1T, const bf16* __restrict__ W2fT,
    const bf16* __restrict__ WH2T, const bf16* __restrict__ gx1,
    const float* __restrict__ pad, const float* __restrict__ b2,
    char* __restrict__ h1f,      // 512 x 131072 B (fragment)
    bf16* __restrict__ gx2ring,  // 16 x [3][1024][64]  (transposed)
    char* __restrict__ hs2f,     // 16 x 131072 B (fragment ring)
    bf16* __restrict__ hs2row,   // [512*64][1024] row-major
    u16* __restrict__ f1s, u16* __restrict__ f1c,
    u16* __restrict__ f2,
    u16* __restrict__ f3s, u16* __restrict__ f3c) {
    extern __shared__ __align__(16) char sW[];   // 48 x 2048 B, swizzled

    const int tid = threadIdx.x, lane = tid & 63, wv = tid >> 6;
    const int role = blockIdx.x >> 6, jg = blockIdx.x & 63;
    const int j0 = jg * 16;
    const int ml = lane & 15, kb = (lane >> 4) * 8;
    const int rbase = (lane >> 4) * 4;
    const int bbase = wv * 16 + rbase;
    const int jml = j0 + ml;

    // ---- load this role's 48x1024 weight slice into LDS (rows gate*16+j)
    const bf16* Wsrc = (role == 0) ? WH1T : (role == 1) ? W2fT : WH2T;
    #pragma unroll 1
    for (int i = 0; i < 24; ++i) {
        int c = tid + 256 * i;
        int rr = c >> 7;
        int off = (c & 127) * 16;
        int gate = rr >> 4, j = rr & 15;
        const bf16* src = Wsrc + (size_t)(gate * 1024 + j0 + j) * 1024 + off / 2;
        *(uint4*)(sW + rr * 2048 + (off ^ ((rr & 7) << 4))) = *(const uint4*)src;
    }
    __syncthreads();   // sW read-only afterwards; waves free-run

    if (role == 0) {
        // ================= layer-1 scan =================
        u16* fown = f1s + wv * 64;
        float hreg[4] = {0.f, 0.f, 0.f, 0.f};
        float gxv[12]; float4 pv;
        #pragma unroll
        for (int r = 0; r < 4; ++r) {
            size_t b = (size_t)(bbase + r);
            gxv[r * 3 + 0] = (float)gx1[b * 3072 + jml];
            gxv[r * 3 + 1] = (float)gx1[b * 3072 + 1024 + jml];
            gxv[r * 3 + 2] = (float)gx1[b * 3072 + 2048 + jml];
        }
        pv = *(const float4*)(pad + bbase);

        for (int t = 0; t < 512; ++t) {
            f32x4 acc[3] = {};
            if (t > 0) {
                poll1(fown, (unsigned)t, lane);
                mm_step(sW, h1f + (size_t)(t - 1) * 131072, wv, lane, kb, ml, acc);
            }
            unsigned short hpk[4];
            #pragma unroll
            for (int r = 0; r < 4; ++r) {
                float rr = 1.f / (1.f + __expf(-(gxv[r * 3 + 0] + acc[0][r])));
                float zz = 1.f / (1.f + __expf(-(gxv[r * 3 + 1] + acc[1][r])));
                float nn = tanhf(gxv[r * 3 + 2] + rr * acc[2][r]);
                float hold = hreg[r];
                float hn = (1.f - zz) * nn + zz * hold;
                float p = (r == 0) ? pv.x : (r == 1) ? pv.y : (r == 2) ? pv.z : pv.w;
                hn = p * hold + (1.f - p) * hn;
                hreg[r] = hn;
                hpk[r] = __builtin_bit_cast(unsigned short, (bf16)hn);
            }
            char* hst = h1f + (size_t)t * 131072;
            #pragma unroll
            for (int r = 0; r < 4; ++r)
                store_pair_frag(hst, bbase + r, jml, hpk[r], ml);
            publish2(fown + jg, f1c + wv * 64 + jg, (unsigned)(t + 1), lane);
            {   // prefetch gx1 + pad for t+1 (cached; drains during next poll)
                int tn = (t < 511) ? t + 1 : 511;
                const bf16* gxt = gx1 + (size_t)tn * 64 * 3072;
                #pragma unroll
                for (int r = 0; r < 4; ++r) {
                    size_t b = (size_t)(bbase + r);
                    gxv[r * 3 + 0] = (float)gxt[b * 3072 + jml];
                    gxv[r * 3 + 1] = (float)gxt[b * 3072 + 1024 + jml];
                    gxv[r * 3 + 2] = (float)gxt[b * 3072 + 2048 + jml];
                }
                pv = *(const float4*)(pad + tn * 64 + bbase);
            }
        }
    } else if (role == 1) {
        // ================= gx2 producer =================
        u16* fsrc = f1c + wv * 64;
        u16* fbp  = f3c + wv * 64;
        for (int t = 0; t < 512; ++t) {
            poll1(fsrc, (unsigned)(t + 1), lane);     // h1[t] ready
            f32x4 acc[3] = {};
            mm_step(sW, h1f + (size_t)t * 131072, wv, lane, kb, ml, acc);
            if (t >= 16)                              // back-pressure only gates STORES
                poll1(fbp, (unsigned)(t - 15), lane);
            // transposed store: [g][col jml][rows bbase..+3] -> one 8B store per g
            bf16* dst = gx2ring + (size_t)(t & 15) * 196608;
            #pragma unroll
            for (int g = 0; g < 3; ++g) {
                unsigned short w0 = __builtin_bit_cast(unsigned short, (bf16)acc[g][0]);
                unsigned short w1 = __builtin_bit_cast(unsigned short, (bf16)acc[g][1]);
                unsigned short w2 = __builtin_bit_cast(unsigned short, (bf16)acc[g][2]);
                unsigned short w3 = __builtin_bit_cast(unsigned short, (bf16)acc[g][3]);
                u64 pk = (u64)w0 | ((u64)w1 << 16) | ((u64)w2 << 32) | ((u64)w3 << 48);
                __hip_atomic_store((u64*)(dst + ((size_t)(g * 1024 + jml)) * 64 + bbase),
                                   pk, __ATOMIC_RELAXED, __HIP_MEMORY_SCOPE_AGENT);
            }
            publish1(f2 + wv * 64 + jg, (unsigned)(t + 1), lane);
        }
    } else {
        // ================= layer-2 scan =================
        u16* fown = f3s + wv * 64;
        u16* fgx  = f2 + wv * 64;
        float b2v[3] = {b2[jml], b2[1024 + jml], b2[2048 + jml]};
        float hreg[4] = {0.f, 0.f, 0.f, 0.f};
        float4 pv = *(const float4*)(pad + bbase);

        for (int t = 0; t < 512; ++t) {
            poll1(fgx, (unsigned)(t + 1), lane);      // gx2 slot t ready
            // issue gx2 loads now; they drain during the fown poll below
            const bf16* gsl = gx2ring + (size_t)(t & 15) * 196608;
            u64 gq[3];
            #pragma unroll
            for (int g = 0; g < 3; ++g)
                gq[g] = __hip_atomic_load(
                    (const u64*)(gsl + ((size_t)(g * 1024 + jml)) * 64 + bbase),
                    __ATOMIC_RELAXED, __HIP_MEMORY_SCOPE_AGENT);
            f32x4 acc[3] = {};
            if (t > 0) {
                poll1(fown, (unsigned)t, lane);       // hs2f[t-1] ready
                mm_step(sW, hs2f + (size_t)((t - 1) & 15) * 131072, wv, lane, kb, ml, acc);
            }
            unsigned short hpk[4];
            #pragma unroll
            for (int r = 0; r < 4; ++r) {
                float gr = (float)__builtin_bit_cast(bf16,
                    (unsigned short)(gq[0] >> (r * 16))) + b2v[0];
                float gz = (float)__builtin_bit_cast(bf16,
                    (unsigned short)(gq[1] >> (r * 16))) + b2v[1];
                float gn = (float)__builtin_bit_cast(bf16,
                    (unsigned short)(gq[2] >> (r * 16))) + b2v[2];
                float rr = 1.f / (1.f + __expf(-(gr + acc[0][r])));
                float zz = 1.f / (1.f + __expf(-(gz + acc[1][r])));
                float nn = tanhf(gn + rr * acc[2][r]);
                float hold = hreg[r];
                float hn = (1.f - zz) * nn + zz * hold;
                float p = (r == 0) ? pv.x : (r == 1) ? pv.y : (r == 2) ? pv.z : pv.w;
                hn = p * hold + (1.f - p) * hn;
                hreg[r] = hn;
                hpk[r] = __builtin_bit_cast(unsigned short, (bf16)hn);
            }
            // fragment store for the recurrence ring (sc)
            char* hstf = hs2f + (size_t)(t & 15) * 131072;
            #pragma unroll
            for (int r = 0; r < 4; ++r)
                store_pair_frag(hstf, bbase + r, jml, hpk[r], ml);
            // row-major plain store for the final GEMM
            bf16* hstr = hs2row + (size_t)t * 65536;
            #pragma unroll
            for (int r = 0; r < 4; ++r) {
                unsigned nb = (unsigned)__shfl_xor((int)(unsigned)hpk[r], 1, 64);
                if ((ml & 1) == 0) {
                    unsigned pk = (unsigned)hpk[r] | (nb << 16);
                    *(unsigned*)(hstr + (size_t)(bbase + r) * 1024 + jml) = pk;
                }
            }
            publish2(fown + jg, f3c + wv * 64 + jg, (unsigned)(t + 1), lane);
            int tn = (t < 511) ? t + 1 : 511;
            pv = *(const float4*)(pad + tn * 64 + bbase);
        }
    }
}

// ---------------------------------------------------------------------------
extern "C" void kernel_launch(void* const* d_in, const int* in_sizes, int n_in,
                              void* d_out, int out_size, void* d_ws, size_t ws_size,
                              hipStream_t stream) {
    const float* x    = (const float*)d_in[0];
    const float* pad  = (const float*)d_in[1];
    const float* Wih1 = (const float*)d_in[2];
    const float* Whh1 = (const float*)d_in[3];
    const float* b1   = (const float*)d_in[4];
    const float* Who1 = (const float*)d_in[5];
    const float* Wih2 = (const float*)d_in[6];
    const float* Whh2 = (const float*)d_in[7];
    const float* b2   = (const float*)d_in[8];
    const float* Who2 = (const float*)d_in[9];
    float* out_f = (float*)d_out;

    char* p = (char*)d_ws;
    bf16* xb      = (bf16*)p; p += (size_t)32768 * 1024 * 2;  //  64MB
    bf16* gxb     = (bf16*)p; p += (size_t)32768 * 3072 * 2;  // 192MB (gx1)
    char* h1f     = p;        p += (size_t)512 * 131072;      //  64MB (fragment)
    bf16* hs2row  = (bf16*)p; p += (size_t)32768 * 1024 * 2;  //  64MB (row-major)
    char* hs2f    = p;        p += (size_t)16 * 131072;       //   2MB (fragment ring)
    bf16* gx2ring = (bf16*)p; p += (size_t)16 * 196608 * 2;   //   6MB
    bf16* WT1     = (bf16*)p; p += (size_t)3072 * 1024 * 2;   //   6MB
    bf16* who1b   = (bf16*)p; p += (size_t)1024 * 1024 * 2;   //   2MB
    bf16* W2fT    = (bf16*)p; p += (size_t)3072 * 1024 * 2;   //   6MB
    bf16* WH1     = (bf16*)p; p += (size_t)3072 * 1024 * 2;   //   6MB
    bf16* WH2     = (bf16*)p; p += (size_t)3072 * 1024 * 2;   //   6MB
    u16* flags = (u16*)p; p += 8192;
    u16* f1s = flags,        * f1c = flags + 256;
    u16* f2  = flags + 512;
    u16* f3s = flags + 768,  * f3c = flags + 1024;

    hipFuncSetAttribute((const void*)gru_fused,
                        hipFuncAttributeMaxDynamicSharedMemorySize, 131072);

    // 1. x -> bf16
    cast_f32_bf16<<<16384, 256, 0, stream>>>(x, xb);
    // 2. gx1 = x @ Wih1 + b1
    transpose_cast<<<dim3(96, 32), 256, 0, stream>>>(Wih1, WT1, 1024, 3072);
    gemm128<true, true><<<dim3(24, 256), 256, 0, stream>>>(
        xb, WT1, b1, gxb, 32768, 3072, 1024);
    // 3. W2fT = (Who1 @ Wih2)^T  (verified recipe)
    transpose_cast<<<dim3(96, 32), 256, 0, stream>>>(Wih2, WT1, 1024, 3072);
    cast_f32_bf16<<<512, 256, 0, stream>>>(Who1, who1b);
    gemm128<true, false><<<dim3(8, 24), 256, 0, stream>>>(
        WT1, who1b, nullptr, W2fT, 3072, 1024, 1024);
    // 4. recurrent weights; Who2T into WT1 (stream-ordered reuse)
    transpose_cast<<<dim3(96, 32), 256, 0, stream>>>(Whh1, WH1, 1024, 3072);
    transpose_cast<<<dim3(96, 32), 256, 0, stream>>>(Whh2, WH2, 1024, 3072);
    transpose_cast<<<dim3(32, 32), 256, 0, stream>>>(Who2, WT1, 1024, 1024);
    hipMemsetAsync(flags, 0, 8192, stream);
    // 5. fused pipelined 2-layer scan (fragment-major h)
    gru_fused<<<192, 256, 98304, stream>>>(WH1, W2fT, WH2, gxb, pad, b2,
                                           h1f, gx2ring, hs2f, hs2row,
                                           f1s, f1c, f2, f3s, f3c);
    // 6. out = hs2 @ Who2 (f32)
    gemm128<false, false><<<dim3(8, 256), 256, 0, stream>>>(
        hs2row, WT1, nullptr, out_f, 32768, 1024, 1024);
}